// Round 1
// baseline (40.640 us; speedup 1.0000x reference)
//
#include <hip/hip_runtime.h>

#define BB 16
#define NN 6000
#define GG 512

__global__ __launch_bounds__(64) void det_assign_kernel(
    const float4* __restrict__ rois,      // (B, N, 4)
    const int*    __restrict__ gt_ids,    // (B, G)
    const float4* __restrict__ gt_boxes,  // (B, G, 4)
    float*        __restrict__ out)       // [B*2*N maxes][B*N pos][B*N neg]
{
    __shared__ float4 s_box[GG];   // y1,x1,y2,x2 ; non-crowd from front, crowd from back
    __shared__ float  s_area[GG];
    __shared__ int    s_cnt[2];    // [0]=non-crowd count, [1]=crowd count

    const int b = blockIdx.y;

    if (threadIdx.x == 0) { s_cnt[0] = 0; s_cnt[1] = 0; }
    __syncthreads();

    // Compact valid GTs for this batch into LDS (order irrelevant for max).
    for (int g = threadIdx.x; g < GG; g += 64) {
        float4 box = gt_boxes[b * GG + g];
        float asum = fabsf(box.x) + fabsf(box.y) + fabsf(box.z) + fabsf(box.w);
        int id = gt_ids[b * GG + g];
        if (asum > 0.0f && id != 0) {
            int idx;
            if (id > 0) idx = atomicAdd(&s_cnt[0], 1);            // non-crowd: front
            else        idx = (GG - 1) - atomicAdd(&s_cnt[1], 1); // crowd: back
            s_box[idx]  = box;
            s_area[idx] = (box.z - box.x) * (box.w - box.y);
        }
    }
    __syncthreads();

    const int n = blockIdx.x * 64 + threadIdx.x;
    if (n >= NN) return;

    const float4 r = rois[b * NN + n];
    const bool vroi = (fabsf(r.x) + fabsf(r.y) + fabsf(r.z) + fabsf(r.w)) > 0.0f;
    const float rarea = (r.z - r.x) * (r.w - r.y);

    const int ncnt = s_cnt[0];
    const int ccnt = s_cnt[1];

    float nc_max = 0.0f;
    float c_max  = 0.0f;

    // Non-crowd max  (all lanes read same LDS word -> broadcast)
    for (int g = 0; g < ncnt; ++g) {
        float4 gb = s_box[g];
        float yy1 = fmaxf(r.x, gb.x);
        float xx1 = fmaxf(r.y, gb.y);
        float yy2 = fminf(r.z, gb.z);
        float xx2 = fminf(r.w, gb.w);
        float inter = fmaxf(yy2 - yy1, 0.0f) * fmaxf(xx2 - xx1, 0.0f);
        float uni = rarea + s_area[g] - inter + 1e-8f;
        float iou = inter * __builtin_amdgcn_rcpf(uni);
        nc_max = fmaxf(nc_max, iou);
    }
    // Crowd max
    for (int g = GG - ccnt; g < GG; ++g) {
        float4 gb = s_box[g];
        float yy1 = fmaxf(r.x, gb.x);
        float xx1 = fmaxf(r.y, gb.y);
        float yy2 = fminf(r.z, gb.z);
        float xx2 = fminf(r.w, gb.w);
        float inter = fmaxf(yy2 - yy1, 0.0f) * fmaxf(xx2 - xx1, 0.0f);
        float uni = rarea + s_area[g] - inter + 1e-8f;
        float iou = inter * __builtin_amdgcn_rcpf(uni);
        c_max = fmaxf(c_max, iou);
    }

    if (!vroi) { nc_max = 0.0f; c_max = 0.0f; }

    // iou_maxes (B, 2, N)
    out[b * 2 * NN + n]      = nc_max;
    out[b * 2 * NN + NN + n] = c_max;
    // positive_mask (B, N), negative_mask (B, N) as 0/1 floats
    const float pos = (vroi && nc_max >= 0.5f) ? 1.0f : 0.0f;
    const float neg = (vroi && nc_max < 0.5f && c_max < 0.001f) ? 1.0f : 0.0f;
    out[BB * 2 * NN + b * NN + n]           = pos;
    out[BB * 2 * NN + BB * NN + b * NN + n] = neg;
}

extern "C" void kernel_launch(void* const* d_in, const int* in_sizes, int n_in,
                              void* d_out, int out_size, void* d_ws, size_t ws_size,
                              hipStream_t stream) {
    const float4* rois     = (const float4*)d_in[0];
    const int*    gt_ids   = (const int*)d_in[1];
    const float4* gt_boxes = (const float4*)d_in[2];
    float*        out      = (float*)d_out;

    dim3 grid((NN + 63) / 64, BB);
    det_assign_kernel<<<grid, 64, 0, stream>>>(rois, gt_ids, gt_boxes, out);
}